// Round 4
// baseline (193.416 us; speedup 1.0000x reference)
//
#include <hip/hip_runtime.h>
#include <math.h>

#define T34 34

// ws float offsets (P' stride 36, rows 0..34; row 34 and cols 34,35 are zero)
#define PW_OFF  0       // P'[35][36]
#define TOK_OFF 1260    // tok_table[10][2]
#define POS_OFF 1280    // pos[35][4] (raw pre-norm positional vectors; entry 34 = zeros)
#define HA_OFF  1420    // hA[2]

// ---------------------------------------------------------------------------
// Kernel A: build the batch-independent tables.
// Attention scores depend only on t because |tok[d]|^2 == A^2 for every digit,
// so rms(x) is digit-independent -> q,k are functions of t only.
// ---------------------------------------------------------------------------
__global__ __launch_bounds__(64) void prep_kernel(
    const float* __restrict__ pA, const float* __restrict__ pStart,
    const float* __restrict__ pStride, const float* __restrict__ zhi,
    const float* __restrict__ spe, const float* __restrict__ qw,
    const float* __restrict__ qph, const float* __restrict__ opA,
    const float* __restrict__ wn, const float* __restrict__ H,
    float* __restrict__ ws)
{
    __shared__ float sK[T34][4];   // k[t] = K0[t]/rho[t]
    __shared__ float sInv[T34];    // 1/rho[t]
    const int t = blockIdx.x;      // 0..33 : this block owns attention row t
    const int s = threadIdx.x;     // 0..63
    const float A = pA[0];

    if (s < T34) {
        // pos table per _SRC/_IDX/_OFFS: t<10 digit(t); 10 zeros; 11..20 digit(t-11);
        // 21 special_pos_equals; 22..31 digit(t-22); 32 z_hi_pos; 33 zeros.
        float p0 = 0.f, p1 = 0.f, p2 = 0.f;
        if (s == 21)      { p0 = spe[0]; p1 = spe[1]; p2 = spe[2]; }
        else if (s == 32) { p0 = zhi[0]; p1 = zhi[1]; p2 = zhi[2]; }
        else if (s != 10 && s != 33) {
            int i = (s < 10) ? s : (s < 21 ? s - 11 : s - 22);
            float a = 0.62831853071795864769f * (float)i;   // 2*pi*i/10
            p0 = 3.5f * cosf(a); p1 = 3.5f * sinf(a); p2 = 0.15f * (float)i;
        }
        float inv = rsqrtf((A*A + p0*p0 + p1*p1 + p2*p2) * 0.2f + 1e-5f);
        float c0 = p0 * wn[2], c1 = p1 * wn[3], c2 = p2 * wn[4];
        #pragma unroll
        for (int j = 0; j < 4; ++j)
            sK[s][j] = (c0*qw[j*3+0] + c1*qw[j*3+1] + c2*qw[j*3+2]) * inv;
        sInv[s] = inv;
        if (s == t) {
            ws[POS_OFF + 4*t + 0] = p0;
            ws[POS_OFF + 4*t + 1] = p1;
            ws[POS_OFF + 4*t + 2] = p2;
            ws[POS_OFF + 4*t + 3] = 0.f;
        }
    }
    __syncthreads();

    // rotate q for row t; k stays unrotated (k = q pre-rotation in the ref)
    float cc = cosf(qph[0]), sn = sinf(qph[0]);
    float k0 = sK[t][0], k1 = sK[t][1], k2 = sK[t][2], k3 = sK[t][3];
    float q0 = k0*cc - k1*sn, q1 = k0*sn + k1*cc;
    float q2 = k2*cc - k3*sn, q3 = k2*sn + k3*cc;

    // causal softmax row t (scores bounded ~|q||k|/2 < ~25 -> max-free exp safe)
    float e = 0.f;
    if (s <= t && s < T34) {
        float d = 0.5f*(q0*sK[s][0] + q1*sK[s][1] + q2*sK[s][2] + q3*sK[s][3]);
        e = expf(d);
    }
    float Z = e;
    #pragma unroll
    for (int off = 1; off < 64; off <<= 1) Z += __shfl_xor(Z, off);
    if (s < 36) ws[PW_OFF + t*36 + s] = (s <= t && s < T34) ? (e / Z) * sInv[s] : 0.f;

    if (t == 0) {
        if (s < 36) ws[PW_OFF + 34*36 + s] = 0.f;     // zero pad row t=34
        if (s < 10) {
            float ang = pStart[0] + (float)s * pStride[0];
            ws[TOK_OFF + 2*s + 0] = A * cosf(ang);
            ws[TOK_OFF + 2*s + 1] = A * sinf(ang);
        } else if (s == 10) {
            // hA[j] = w[j] * sum_h H[j][h]*out_proj_A[h]  (collapses out@A@B to g*B)
            float a0 = 0.f, a1 = 0.f;
            #pragma unroll
            for (int h = 0; h < 5; ++h) { a0 += H[h]*opA[h]; a1 += H[5+h]*opA[h]; }
            ws[HA_OFF + 0] = a0 * wn[0];
            ws[HA_OFF + 1] = a1 * wn[1];
        } else if (s == 11) {
            ws[POS_OFF + 4*34 + 0] = 0.f;             // zero pad pos entry t=34
            ws[POS_OFF + 4*34 + 1] = 0.f;
            ws[POS_OFF + 4*34 + 2] = 0.f;
            ws[POS_OFF + 4*34 + 3] = 0.f;
        }
    }
}

// tanh-form gelu via hardware exp; |err vs exact| ~1e-3, far under threshold
__device__ __forceinline__ float gelu_fast(float z) {
    float w = 0.7978845608028654f * (z + 0.044715f * z * z * z);
    float e = __expf(2.f * w);
    float th = 1.f - 2.f / (e + 1.f);
    return 0.5f * z * (1.f + th);
}

// ---------------------------------------------------------------------------
// Kernel B: one block = 64 batches x ALL 34 t's, 8 waves (32 waves/CU = 100%
// slot occupancy at 4 blocks/CU). Wave ty owns t = ty + 8j (j=0..4), with
// pad slots t>=34 clamped to P' zero row 34 (finite math, store skipped).
//  phase 0: digit LUT + tok table copy + su pad zeroing
//  phase 1: idx staged once (int4 coalesced) -> su via LDS LUT gather
//  phase 2: attention s-loop as 9x ds_read_b128 + uniform s_load P rows,
//           5 acc pairs, scalar epilogue (fast gelu) -> (p0,p1) float2 to LDS
//  phase 3: segment writer: thread = (batch, t-pair) = 20 contiguous floats;
//           2x ds_read_b64 + 5x global_store_dwordx4, full line coverage
// ---------------------------------------------------------------------------
__global__ __launch_bounds__(512, 8) void micro_kernel(
    const int*  __restrict__ idx,
    const float* __restrict__ pA, const float* __restrict__ pStart,
    const float* __restrict__ pStride,
    const float* __restrict__ opB, const float* __restrict__ wn,
    const float* __restrict__ fc1, const float* __restrict__ H,
    const float* __restrict__ ws,
    float* __restrict__ out)
{
    __shared__ unsigned su[64*36];   // [b'][s] packed bf16x2 tok emb (s=34,35 zero)
    __shared__ float2   prv[64*36];  // [b'][t] (p0,p1); only t<34 written/read
    __shared__ float    stk[20];     // tok_table copy (f32)
    __shared__ unsigned lut[10];     // packed bf16x2 tok emb per digit
    const int tid  = threadIdx.x;    // 0..511
    const int lane = tid & 63;       // b'
    const int ty   = tid >> 6;       // 0..7
    const int b0   = blockIdx.x << 6;

    // ---- phase 0: tiny tables
    if (tid < 20) stk[tid] = ws[TOK_OFF + tid];
    if (tid >= 64 && tid < 74) {                 // wave 1 builds the digit LUT
        int d = tid - 64;
        float ang = pStart[0] + (float)d * pStride[0];
        float ux = pA[0]*__cosf(ang), uy = pA[0]*__sinf(ang);
        unsigned hx = (__float_as_uint(ux) + 0x8000u) >> 16;
        unsigned hy = (__float_as_uint(uy) + 0x8000u) & 0xffff0000u;
        lut[d] = hy | hx;
    }
    if (tid < 128) su[(tid >> 1)*36 + 34 + (tid & 1)] = 0u;   // zero s=34,35 pad
    __syncthreads();

    // ---- phase 1: stage 64x34 idx (int4 coalesced) -> LUT gather into su
    {
        const int4* src4 = (const int4*)(idx + (size_t)b0*T34);
        for (int e4 = tid; e4 < 544; e4 += 512) {            // 64*34/4
            int4 d4 = src4[e4];
            int e = e4 << 2;
            #pragma unroll
            for (int k = 0; k < 4; ++k) {
                int d = (k==0) ? d4.x : (k==1) ? d4.y : (k==2) ? d4.z : d4.w;
                int ee = e + k;
                unsigned bp = (unsigned)ee / 34u;
                int s = ee - (int)(bp*34u);
                su[bp*36u + (unsigned)s] = lut[d];           // <=10 distinct addrs: multicast
            }
        }
    }
    __syncthreads();

    // ---- phase 2: attention + epilogue for t = tyu + 8j, j=0..4
    {
        const int tyu = __builtin_amdgcn_readfirstlane(ty);  // wave-uniform
        const uint4* __restrict__ srow4 = (const uint4*)(su + lane*36);
        int row[5];
        #pragma unroll
        for (int j = 0; j < 5; ++j) {
            int t = tyu + 8*j;
            row[j] = (t < 34) ? t : 34;                      // clamp pads to zero row
        }

        float mx[5] = {0,0,0,0,0}, my[5] = {0,0,0,0,0};
        #pragma unroll
        for (int s4 = 0; s4 < 9; ++s4) {
            uint4 pk4 = srow4[s4];                           // ds_read_b128
            #pragma unroll
            for (int k = 0; k < 4; ++k) {
                unsigned pk = (k==0) ? pk4.x : (k==1) ? pk4.y : (k==2) ? pk4.z : pk4.w;
                float ux = __uint_as_float(pk << 16);
                float uy = __uint_as_float(pk & 0xffff0000u);
                int s = s4*4 + k;
                #pragma unroll
                for (int j = 0; j < 5; ++j) {
                    float P = ws[PW_OFF + row[j]*36 + s];    // uniform -> s_load
                    mx[j] = fmaf(P, ux, mx[j]);
                    my[j] = fmaf(P, uy, my[j]);
                }
            }
        }

        const float hA0 = ws[HA_OFF], hA1 = ws[HA_OFF+1];
        const float w0=wn[0], w1=wn[1], w2=wn[2], w3=wn[3], w4=wn[4];
        const float ob0=opB[0], ob1=opB[1], ob2=opB[2], ob3=opB[3], ob4=opB[4];
        const unsigned* __restrict__ srow = su + lane*36;

        #pragma unroll
        for (int j = 0; j < 5; ++j) {
            const int t  = tyu + 8*j;          // uniform
            const int rc = row[j];             // clamped (pad -> zero entries)
            float g = mx[j]*hA0 + my[j]*hA1;   // out5 @ out_proj_A (collapsed)
            unsigned pkt = srow[rc];
            float x0 = __uint_as_float(pkt << 16)         + g*ob0;
            float x1 = __uint_as_float(pkt & 0xffff0000u) + g*ob1;
            float x2 = ws[POS_OFF + 4*rc + 0] + g*ob2;
            float x3 = ws[POS_OFF + 4*rc + 1] + g*ob3;
            float x4 = ws[POS_OFF + 4*rc + 2] + g*ob4;

            float inv1 = rsqrtf((x0*x0+x1*x1+x2*x2+x3*x3+x4*x4)*0.2f + 1e-5f);
            float h0=x0*inv1*w0, h1=x1*inv1*w1, h2=x2*inv1*w2, h3=x3*inv1*w3, h4=x4*inv1*w4;
            float z0 = h0*fc1[0]+h1*fc1[1]+h2*fc1[2]+h3*fc1[3]+h4*fc1[4];
            float z1 = h0*fc1[5]+h1*fc1[6]+h2*fc1[7]+h3*fc1[8]+h4*fc1[9];
            float g0 = gelu_fast(z0);
            float g1 = gelu_fast(z1);
            x0 += g0*H[0] + g1*H[5];
            x1 += g0*H[1] + g1*H[6];
            x2 += g0*H[2] + g1*H[7];
            x3 += g0*H[3] + g1*H[8];
            x4 += g0*H[4] + g1*H[9];
            float inv2 = rsqrtf((x0*x0+x1*x1+x2*x2+x3*x3+x4*x4)*0.2f + 1e-5f);
            h0=x0*inv2*w0; h1=x1*inv2*w1; h2=x2*inv2*w2; h3=x3*inv2*w3; h4=x4*inv2*w4;
            float p0 = h0*H[0]+h1*H[1]+h2*H[2]+h3*H[3]+h4*H[4];
            float p1 = h0*H[5]+h1*H[6]+h2*H[7]+h3*H[8]+h4*H[9];
            if (t < 34) prv[lane*36 + t] = make_float2(p0, p1);  // uniform branch
        }
    }
    __syncthreads();

    // ---- phase 3: segment writer (thread = one batch x t-pair, 20 floats)
    {
        float4* __restrict__ o4 = (float4*)out + (size_t)b0*85; // 340 f/row
        for (int e = tid; e < 1088; e += 512) {                 // 64 bp * 17 segs
            int bp = e / 17;
            int sg = e - 17*bp;
            float2 pa = prv[bp*36 + 2*sg];       // t = 2*sg
            float2 pb = prv[bp*36 + 2*sg + 1];   // t = 2*sg+1
            #pragma unroll
            for (int k = 0; k < 5; ++k) {
                float4 v;
                #pragma unroll
                for (int c4 = 0; c4 < 4; ++c4) {
                    int f = 4*k + c4;                    // 0..19 (compile-time)
                    float2 p = (f < 10) ? pa : pb;
                    int c = (f < 10) ? f : f - 10;
                    ((float*)&v)[c4] = p.x*stk[2*c] + p.y*stk[2*c+1];
                }
                o4[bp*85 + sg*5 + k] = v;
            }
        }
    }
}

extern "C" void kernel_launch(void* const* d_in, const int* in_sizes, int n_in,
                              void* d_out, int out_size, void* d_ws, size_t ws_size,
                              hipStream_t stream)
{
    const int*   idx  = (const int*)  d_in[0];
    const float* pA   = (const float*)d_in[1];   // tok_arc_A
    const float* pSt  = (const float*)d_in[2];   // tok_arc_start
    const float* pSd  = (const float*)d_in[3];   // tok_arc_stride
    const float* zhi  = (const float*)d_in[4];   // z_hi_pos (3)
    const float* spe  = (const float*)d_in[5];   // special_pos_equals (3)
    const float* qw   = (const float*)d_in[6];   // q_proj_w (4x3)
    const float* qph  = (const float*)d_in[7];   // q_phase_angle (1)
    const float* opA  = (const float*)d_in[8];   // out_proj_A (5x1)
    const float* opB  = (const float*)d_in[9];   // out_proj_B (1x5)
    const float* wn   = (const float*)d_in[10];  // norm_weight (5)
    const float* fc1  = (const float*)d_in[11];  // fc1_w (2x5)
    const float* H    = (const float*)d_in[12];  // head_proj_w (2x5)
    float* ws  = (float*)d_ws;
    float* out = (float*)d_out;

    hipLaunchKernelGGL(prep_kernel, dim3(34), dim3(64), 0, stream,
                       pA, pSt, pSd, zhi, spe, qw, qph, opA, wn, H, ws);
    hipLaunchKernelGGL(micro_kernel, dim3(1024), dim3(512), 0, stream,
                       idx, pA, pSt, pSd, opB, wn, fc1, H, ws, out);
}

// Round 6
// 183.231 us; speedup vs baseline: 1.0556x; 1.0556x over previous
//
#include <hip/hip_runtime.h>
#include <math.h>

#define T34 34

typedef float vfloat4 __attribute__((ext_vector_type(4)));  // native vec for nontemporal builtin

// ws float offsets (P' stride 36, rows 0..34; row 34 and cols 34,35 are zero)
#define PW_OFF  0       // P'[35][36]
#define TOK_OFF 1260    // tok_table[10][2]
#define POS_OFF 1280    // pos[35][4] (raw pre-norm positional vectors; entry 34 = zeros)
#define HA_OFF  1420    // hA[2]

// ---------------------------------------------------------------------------
// Kernel A: build the batch-independent tables.
// Attention scores depend only on t because |tok[d]|^2 == A^2 for every digit,
// so rms(x) is digit-independent -> q,k are functions of t only.
// ---------------------------------------------------------------------------
__global__ __launch_bounds__(64) void prep_kernel(
    const float* __restrict__ pA, const float* __restrict__ pStart,
    const float* __restrict__ pStride, const float* __restrict__ zhi,
    const float* __restrict__ spe, const float* __restrict__ qw,
    const float* __restrict__ qph, const float* __restrict__ opA,
    const float* __restrict__ wn, const float* __restrict__ H,
    float* __restrict__ ws)
{
    __shared__ float sK[T34][4];   // k[t] = K0[t]/rho[t]
    __shared__ float sInv[T34];    // 1/rho[t]
    const int t = blockIdx.x;      // 0..33 : this block owns attention row t
    const int s = threadIdx.x;     // 0..63
    const float A = pA[0];

    if (s < T34) {
        // pos table per _SRC/_IDX/_OFFS: t<10 digit(t); 10 zeros; 11..20 digit(t-11);
        // 21 special_pos_equals; 22..31 digit(t-22); 32 z_hi_pos; 33 zeros.
        float p0 = 0.f, p1 = 0.f, p2 = 0.f;
        if (s == 21)      { p0 = spe[0]; p1 = spe[1]; p2 = spe[2]; }
        else if (s == 32) { p0 = zhi[0]; p1 = zhi[1]; p2 = zhi[2]; }
        else if (s != 10 && s != 33) {
            int i = (s < 10) ? s : (s < 21 ? s - 11 : s - 22);
            float a = 0.62831853071795864769f * (float)i;   // 2*pi*i/10
            p0 = 3.5f * cosf(a); p1 = 3.5f * sinf(a); p2 = 0.15f * (float)i;
        }
        float inv = rsqrtf((A*A + p0*p0 + p1*p1 + p2*p2) * 0.2f + 1e-5f);
        float c0 = p0 * wn[2], c1 = p1 * wn[3], c2 = p2 * wn[4];
        #pragma unroll
        for (int j = 0; j < 4; ++j)
            sK[s][j] = (c0*qw[j*3+0] + c1*qw[j*3+1] + c2*qw[j*3+2]) * inv;
        sInv[s] = inv;
        if (s == t) {
            ws[POS_OFF + 4*t + 0] = p0;
            ws[POS_OFF + 4*t + 1] = p1;
            ws[POS_OFF + 4*t + 2] = p2;
            ws[POS_OFF + 4*t + 3] = 0.f;
        }
    }
    __syncthreads();

    // rotate q for row t; k stays unrotated (k = q pre-rotation in the ref)
    float cc = cosf(qph[0]), sn = sinf(qph[0]);
    float k0 = sK[t][0], k1 = sK[t][1], k2 = sK[t][2], k3 = sK[t][3];
    float q0 = k0*cc - k1*sn, q1 = k0*sn + k1*cc;
    float q2 = k2*cc - k3*sn, q3 = k2*sn + k3*cc;

    // causal softmax row t (scores bounded ~|q||k|/2 < ~25 -> max-free exp safe)
    float e = 0.f;
    if (s <= t && s < T34) {
        float d = 0.5f*(q0*sK[s][0] + q1*sK[s][1] + q2*sK[s][2] + q3*sK[s][3]);
        e = expf(d);
    }
    float Z = e;
    #pragma unroll
    for (int off = 1; off < 64; off <<= 1) Z += __shfl_xor(Z, off);
    if (s < 36) ws[PW_OFF + t*36 + s] = (s <= t && s < T34) ? (e / Z) * sInv[s] : 0.f;

    if (t == 0) {
        if (s < 36) ws[PW_OFF + 34*36 + s] = 0.f;     // zero pad row t=34
        if (s < 10) {
            float ang = pStart[0] + (float)s * pStride[0];
            ws[TOK_OFF + 2*s + 0] = A * cosf(ang);
            ws[TOK_OFF + 2*s + 1] = A * sinf(ang);
        } else if (s == 10) {
            // hA[j] = w[j] * sum_h H[j][h]*out_proj_A[h]  (collapses out@A@B to g*B)
            float a0 = 0.f, a1 = 0.f;
            #pragma unroll
            for (int h = 0; h < 5; ++h) { a0 += H[h]*opA[h]; a1 += H[5+h]*opA[h]; }
            ws[HA_OFF + 0] = a0 * wn[0];
            ws[HA_OFF + 1] = a1 * wn[1];
        } else if (s == 11) {
            ws[POS_OFF + 4*34 + 0] = 0.f;             // zero pad pos entry t=34
            ws[POS_OFF + 4*34 + 1] = 0.f;
            ws[POS_OFF + 4*34 + 2] = 0.f;
            ws[POS_OFF + 4*34 + 3] = 0.f;
        }
    }
}

// tanh-form gelu via hardware exp; |err vs exact| ~1e-3, far under threshold
__device__ __forceinline__ float gelu_fast(float z) {
    float w = 0.7978845608028654f * (z + 0.044715f * z * z * z);
    float e = __expf(2.f * w);
    float th = 1.f - 2.f / (e + 1.f);
    return 0.5f * z * (1.f + th);
}

// ---------------------------------------------------------------------------
// Kernel B: one block = 64 batches x ALL 34 t's, 8 waves (32 waves/CU = 100%
// slot occupancy at 4 blocks/CU). Wave ty owns t = ty + 8j (j=0..4), pads
// clamped to P' zero row 34 (finite math, store skipped).
//  phase 0: digit LUT + tok table copy + su pad zeroing
//  phase 1: idx staged once (int4 coalesced) -> su via LDS LUT gather
//  phase 2: attention s-loop as 9x ds_read_b128 + uniform s_load P rows,
//           5 acc pairs, scalar epilogue (fast gelu) -> (p0,p1) float2 to LDS
//  phase 3: LANE-CONSECUTIVE float4 expansion of the block's contiguous
//           87 KB span (R3 pattern: full per-instruction line coverage; the
//           R4 strided segment writer caused RMW FETCH=124MB - never again).
//           Nontemporal: output is a pure 89 MB stream, keep L2 for idx.
// ---------------------------------------------------------------------------
__global__ __launch_bounds__(512, 8) void micro_kernel(
    const int*  __restrict__ idx,
    const float* __restrict__ pA, const float* __restrict__ pStart,
    const float* __restrict__ pStride,
    const float* __restrict__ opB, const float* __restrict__ wn,
    const float* __restrict__ fc1, const float* __restrict__ H,
    const float* __restrict__ ws,
    float* __restrict__ out)
{
    __shared__ unsigned su[64*36];   // [b'][s] packed bf16x2 tok emb (s=34,35 zero)
    __shared__ float2   prv[64*36];  // [b'][t] (p0,p1); only t<34 written/read
    __shared__ float    stk[20];     // tok_table copy (f32)
    __shared__ unsigned lut[10];     // packed bf16x2 tok emb per digit
    const int tid  = threadIdx.x;    // 0..511
    const int lane = tid & 63;       // b'
    const int ty   = tid >> 6;       // 0..7
    const int b0   = blockIdx.x << 6;

    // ---- phase 0: tiny tables
    if (tid < 20) stk[tid] = ws[TOK_OFF + tid];
    if (tid >= 64 && tid < 74) {                 // wave 1 builds the digit LUT
        int d = tid - 64;
        float ang = pStart[0] + (float)d * pStride[0];
        float ux = pA[0]*__cosf(ang), uy = pA[0]*__sinf(ang);
        unsigned hx = (__float_as_uint(ux) + 0x8000u) >> 16;
        unsigned hy = (__float_as_uint(uy) + 0x8000u) & 0xffff0000u;
        lut[d] = hy | hx;
    }
    if (tid < 128) su[(tid >> 1)*36 + 34 + (tid & 1)] = 0u;   // zero s=34,35 pad
    __syncthreads();

    // ---- phase 1: stage 64x34 idx (int4 coalesced) -> LUT gather into su
    {
        const int4* src4 = (const int4*)(idx + (size_t)b0*T34);
        for (int e4 = tid; e4 < 544; e4 += 512) {            // 64*34/4
            int4 d4 = src4[e4];
            int e = e4 << 2;
            #pragma unroll
            for (int k = 0; k < 4; ++k) {
                int d = (k==0) ? d4.x : (k==1) ? d4.y : (k==2) ? d4.z : d4.w;
                int ee = e + k;
                unsigned bp = (unsigned)ee / 34u;
                int s = ee - (int)(bp*34u);
                su[bp*36u + (unsigned)s] = lut[d];           // <=10 distinct addrs: multicast
            }
        }
    }
    __syncthreads();

    // ---- phase 2: attention + epilogue for t = tyu + 8j, j=0..4
    {
        const int tyu = __builtin_amdgcn_readfirstlane(ty);  // wave-uniform
        const uint4* __restrict__ srow4 = (const uint4*)(su + lane*36);
        int row[5];
        #pragma unroll
        for (int j = 0; j < 5; ++j) {
            int t = tyu + 8*j;
            row[j] = (t < 34) ? t : 34;                      // clamp pads to zero row
        }

        float mx[5] = {0,0,0,0,0}, my[5] = {0,0,0,0,0};
        #pragma unroll
        for (int s4 = 0; s4 < 9; ++s4) {
            uint4 pk4 = srow4[s4];                           // ds_read_b128
            #pragma unroll
            for (int k = 0; k < 4; ++k) {
                unsigned pk = (k==0) ? pk4.x : (k==1) ? pk4.y : (k==2) ? pk4.z : pk4.w;
                float ux = __uint_as_float(pk << 16);
                float uy = __uint_as_float(pk & 0xffff0000u);
                int s = s4*4 + k;
                #pragma unroll
                for (int j = 0; j < 5; ++j) {
                    float P = ws[PW_OFF + row[j]*36 + s];    // uniform -> s_load
                    mx[j] = fmaf(P, ux, mx[j]);
                    my[j] = fmaf(P, uy, my[j]);
                }
            }
        }

        const float hA0 = ws[HA_OFF], hA1 = ws[HA_OFF+1];
        const float w0=wn[0], w1=wn[1], w2=wn[2], w3=wn[3], w4=wn[4];
        const float ob0=opB[0], ob1=opB[1], ob2=opB[2], ob3=opB[3], ob4=opB[4];
        const unsigned* __restrict__ srow = su + lane*36;

        #pragma unroll
        for (int j = 0; j < 5; ++j) {
            const int t  = tyu + 8*j;          // uniform
            const int rc = row[j];             // clamped (pad -> zero entries)
            float g = mx[j]*hA0 + my[j]*hA1;   // out5 @ out_proj_A (collapsed)
            unsigned pkt = srow[rc];
            float x0 = __uint_as_float(pkt << 16)         + g*ob0;
            float x1 = __uint_as_float(pkt & 0xffff0000u) + g*ob1;
            float x2 = ws[POS_OFF + 4*rc + 0] + g*ob2;
            float x3 = ws[POS_OFF + 4*rc + 1] + g*ob3;
            float x4 = ws[POS_OFF + 4*rc + 2] + g*ob4;

            float inv1 = rsqrtf((x0*x0+x1*x1+x2*x2+x3*x3+x4*x4)*0.2f + 1e-5f);
            float h0=x0*inv1*w0, h1=x1*inv1*w1, h2=x2*inv1*w2, h3=x3*inv1*w3, h4=x4*inv1*w4;
            float z0 = h0*fc1[0]+h1*fc1[1]+h2*fc1[2]+h3*fc1[3]+h4*fc1[4];
            float z1 = h0*fc1[5]+h1*fc1[6]+h2*fc1[7]+h3*fc1[8]+h4*fc1[9];
            float g0 = gelu_fast(z0);
            float g1 = gelu_fast(z1);
            x0 += g0*H[0] + g1*H[5];
            x1 += g0*H[1] + g1*H[6];
            x2 += g0*H[2] + g1*H[7];
            x3 += g0*H[3] + g1*H[8];
            x4 += g0*H[4] + g1*H[9];
            float inv2 = rsqrtf((x0*x0+x1*x1+x2*x2+x3*x3+x4*x4)*0.2f + 1e-5f);
            h0=x0*inv2*w0; h1=x1*inv2*w1; h2=x2*inv2*w2; h3=x3*inv2*w3; h4=x4*inv2*w4;
            float p0 = h0*H[0]+h1*H[1]+h2*H[2]+h3*H[3]+h4*H[4];
            float p1 = h0*H[5]+h1*H[6]+h2*H[7]+h3*H[8]+h4*H[9];
            if (t < 34) prv[lane*36 + t] = make_float2(p0, p1);  // uniform branch
        }
    }
    __syncthreads();

    // ---- phase 3: lane-consecutive float4 write of the contiguous span
    {
        vfloat4* __restrict__ o4 = (vfloat4*)out + (size_t)b0*85;  // 340 f/row
        for (int e4 = tid; e4 < 5440; e4 += 512) {                 // 64*85
            int bp = e4 / 85;
            int r4 = e4 - 85*bp;
            int f0 = 4*r4;
            int ta = f0 / 10;
            int tb = (f0 + 3) / 10;          // ta or ta+1
            float2 pa = prv[bp*36 + ta];
            float2 pb = prv[bp*36 + tb];
            vfloat4 v;
            #pragma unroll
            for (int k = 0; k < 4; ++k) {
                int f = f0 + k;
                int t = f / 10;
                int c = f - 10*t;
                float2 p = (t == ta) ? pa : pb;
                v[k] = p.x*stk[2*c] + p.y*stk[2*c+1];
            }
            __builtin_nontemporal_store(v, &o4[e4]);
        }
    }
}

extern "C" void kernel_launch(void* const* d_in, const int* in_sizes, int n_in,
                              void* d_out, int out_size, void* d_ws, size_t ws_size,
                              hipStream_t stream)
{
    const int*   idx  = (const int*)  d_in[0];
    const float* pA   = (const float*)d_in[1];   // tok_arc_A
    const float* pSt  = (const float*)d_in[2];   // tok_arc_start
    const float* pSd  = (const float*)d_in[3];   // tok_arc_stride
    const float* zhi  = (const float*)d_in[4];   // z_hi_pos (3)
    const float* spe  = (const float*)d_in[5];   // special_pos_equals (3)
    const float* qw   = (const float*)d_in[6];   // q_proj_w (4x3)
    const float* qph  = (const float*)d_in[7];   // q_phase_angle (1)
    const float* opA  = (const float*)d_in[8];   // out_proj_A (5x1)
    const float* opB  = (const float*)d_in[9];   // out_proj_B (1x5)
    const float* wn   = (const float*)d_in[10];  // norm_weight (5)
    const float* fc1  = (const float*)d_in[11];  // fc1_w (2x5)
    const float* H    = (const float*)d_in[12];  // head_proj_w (2x5)
    float* ws  = (float*)d_ws;
    float* out = (float*)d_out;

    hipLaunchKernelGGL(prep_kernel, dim3(34), dim3(64), 0, stream,
                       pA, pSt, pSd, zhi, spe, qw, qph, opA, wn, H, ws);
    hipLaunchKernelGGL(micro_kernel, dim3(1024), dim3(512), 0, stream,
                       idx, pA, pSt, pSd, opB, wn, fc1, H, ws, out);
}

// Round 7
// 142.291 us; speedup vs baseline: 1.3593x; 1.2877x over previous
//
#include <hip/hip_runtime.h>
#include <math.h>

#define T34 34

typedef float vfloat4 __attribute__((ext_vector_type(4)));  // native vec for nontemporal builtin

// ws float offsets (P' stride 36, rows 0..34; row 34 and cols 34,35 are zero)
#define PW_OFF  0       // P'[35][36]
#define TOK_OFF 1260    // tok_table[10][2]
#define POS_OFF 1280    // pos[35][4] (raw pre-norm positional vectors; entry 34 = zeros)
#define HA_OFF  1420    // hA[2]

// ---------------------------------------------------------------------------
// Kernel A: build the batch-independent tables.
// Attention scores depend only on t because |tok[d]|^2 == A^2 for every digit,
// so rms(x) is digit-independent -> q,k are functions of t only.
// ---------------------------------------------------------------------------
__global__ __launch_bounds__(64) void prep_kernel(
    const float* __restrict__ pA, const float* __restrict__ pStart,
    const float* __restrict__ pStride, const float* __restrict__ zhi,
    const float* __restrict__ spe, const float* __restrict__ qw,
    const float* __restrict__ qph, const float* __restrict__ opA,
    const float* __restrict__ wn, const float* __restrict__ H,
    float* __restrict__ ws)
{
    __shared__ float sK[T34][4];   // k[t] = K0[t]/rho[t]
    __shared__ float sInv[T34];    // 1/rho[t]
    const int t = blockIdx.x;      // 0..33 : this block owns attention row t
    const int s = threadIdx.x;     // 0..63
    const float A = pA[0];

    if (s < T34) {
        // pos table per _SRC/_IDX/_OFFS: t<10 digit(t); 10 zeros; 11..20 digit(t-11);
        // 21 special_pos_equals; 22..31 digit(t-22); 32 z_hi_pos; 33 zeros.
        float p0 = 0.f, p1 = 0.f, p2 = 0.f;
        if (s == 21)      { p0 = spe[0]; p1 = spe[1]; p2 = spe[2]; }
        else if (s == 32) { p0 = zhi[0]; p1 = zhi[1]; p2 = zhi[2]; }
        else if (s != 10 && s != 33) {
            int i = (s < 10) ? s : (s < 21 ? s - 11 : s - 22);
            float a = 0.62831853071795864769f * (float)i;   // 2*pi*i/10
            p0 = 3.5f * cosf(a); p1 = 3.5f * sinf(a); p2 = 0.15f * (float)i;
        }
        float inv = rsqrtf((A*A + p0*p0 + p1*p1 + p2*p2) * 0.2f + 1e-5f);
        float c0 = p0 * wn[2], c1 = p1 * wn[3], c2 = p2 * wn[4];
        #pragma unroll
        for (int j = 0; j < 4; ++j)
            sK[s][j] = (c0*qw[j*3+0] + c1*qw[j*3+1] + c2*qw[j*3+2]) * inv;
        sInv[s] = inv;
        if (s == t) {
            ws[POS_OFF + 4*t + 0] = p0;
            ws[POS_OFF + 4*t + 1] = p1;
            ws[POS_OFF + 4*t + 2] = p2;
            ws[POS_OFF + 4*t + 3] = 0.f;
        }
    }
    __syncthreads();

    // rotate q for row t; k stays unrotated (k = q pre-rotation in the ref)
    float cc = cosf(qph[0]), sn = sinf(qph[0]);
    float k0 = sK[t][0], k1 = sK[t][1], k2 = sK[t][2], k3 = sK[t][3];
    float q0 = k0*cc - k1*sn, q1 = k0*sn + k1*cc;
    float q2 = k2*cc - k3*sn, q3 = k2*sn + k3*cc;

    // causal softmax row t (scores bounded ~|q||k|/2 < ~25 -> max-free exp safe)
    float e = 0.f;
    if (s <= t && s < T34) {
        float d = 0.5f*(q0*sK[s][0] + q1*sK[s][1] + q2*sK[s][2] + q3*sK[s][3]);
        e = expf(d);
    }
    float Z = e;
    #pragma unroll
    for (int off = 1; off < 64; off <<= 1) Z += __shfl_xor(Z, off);
    if (s < 36) ws[PW_OFF + t*36 + s] = (s <= t && s < T34) ? (e / Z) * sInv[s] : 0.f;

    if (t == 0) {
        if (s < 36) ws[PW_OFF + 34*36 + s] = 0.f;     // zero pad row t=34
        if (s < 10) {
            float ang = pStart[0] + (float)s * pStride[0];
            ws[TOK_OFF + 2*s + 0] = A * cosf(ang);
            ws[TOK_OFF + 2*s + 1] = A * sinf(ang);
        } else if (s == 10) {
            // hA[j] = w[j] * sum_h H[j][h]*out_proj_A[h]  (collapses out@A@B to g*B)
            float a0 = 0.f, a1 = 0.f;
            #pragma unroll
            for (int h = 0; h < 5; ++h) { a0 += H[h]*opA[h]; a1 += H[5+h]*opA[h]; }
            ws[HA_OFF + 0] = a0 * wn[0];
            ws[HA_OFF + 1] = a1 * wn[1];
        } else if (s == 11) {
            ws[POS_OFF + 4*34 + 0] = 0.f;             // zero pad pos entry t=34
            ws[POS_OFF + 4*34 + 1] = 0.f;
            ws[POS_OFF + 4*34 + 2] = 0.f;
            ws[POS_OFF + 4*34 + 3] = 0.f;
        }
    }
}

// tanh-form gelu via hardware exp; |err vs exact| ~1e-3, far under threshold
__device__ __forceinline__ float gelu_fast(float z) {
    float w = 0.7978845608028654f * (z + 0.044715f * z * z * z);
    float e = __expf(2.f * w);
    float th = 1.f - 2.f / (e + 1.f);
    return 0.5f * z * (1.f + th);
}

// ---------------------------------------------------------------------------
// Kernel B: one block = 64 batches x ALL 34 t's, 7 waves of 64 (bench-R3
// structure, the counter-verified-clean lineage; the 512-thread restructure
// inflated FETCH to 125MB for reasons TBD - reverted).
// Wave ty owns t = ty+7j (j=0..4); t=34 is the P' zero row / prv pad slot.
//  phase 0: digit LUT + tok table copy + su pad zeroing
//  phase 1: idx staged once (int4 coalesced) -> su via LDS LUT gather
//  phase 2: attention s-loop: 9x ds_read_b128 + literal-offset s_load P rows,
//           5 acc pairs, scalar epilogue (fast gelu) -> float2 prv in LDS
//  phase 3: lane-consecutive nontemporal float4 expansion of the block's
//           contiguous 87 KB output span
// ---------------------------------------------------------------------------
__global__ __launch_bounds__(448) void micro_kernel(
    const int*  __restrict__ idx,
    const float* __restrict__ pA, const float* __restrict__ pStart,
    const float* __restrict__ pStride,
    const float* __restrict__ opB, const float* __restrict__ wn,
    const float* __restrict__ fc1, const float* __restrict__ H,
    const float* __restrict__ ws,
    float* __restrict__ out)
{
    __shared__ unsigned su[64*36];   // [b'][s] packed bf16x2 tok emb (s=34,35 zero)
    __shared__ float2   prv[64*35];  // [b'][t] (p0,p1); t=34 pad slot
    __shared__ float    stk[20];     // tok_table copy (f32)
    __shared__ unsigned lut[10];     // packed bf16x2 tok emb per digit
    const int lane = threadIdx.x;    // b' 0..63
    const int ty   = threadIdx.y;    // 0..6
    const int tid  = ty*64 + lane;
    const int b0   = blockIdx.x << 6;

    // ---- phase 0: tiny tables
    if (tid < 20) stk[tid] = ws[TOK_OFF + tid];
    if (tid >= 64 && tid < 74) {                 // wave 1 builds the digit LUT
        int d = tid - 64;
        float ang = pStart[0] + (float)d * pStride[0];
        float ux = pA[0]*__cosf(ang), uy = pA[0]*__sinf(ang);
        unsigned hx = (__float_as_uint(ux) + 0x8000u) >> 16;
        unsigned hy = (__float_as_uint(uy) + 0x8000u) & 0xffff0000u;
        lut[d] = hy | hx;
    }
    if (tid < 128) su[(tid >> 1)*36 + 34 + (tid & 1)] = 0u;   // zero s=34,35 pad
    __syncthreads();

    // ---- phase 1: stage 64x34 idx (int4 coalesced) -> LUT gather into su
    {
        const int4* src4 = (const int4*)(idx + (size_t)b0*T34);
        for (int e4 = tid; e4 < 544; e4 += 448) {            // 64*34/4
            int4 d4 = src4[e4];
            int e = e4 << 2;
            #pragma unroll
            for (int k = 0; k < 4; ++k) {
                int d = (k==0) ? d4.x : (k==1) ? d4.y : (k==2) ? d4.z : d4.w;
                int ee = e + k;
                unsigned bp = (unsigned)ee / 34u;
                int s = ee - (int)(bp*34u);
                su[bp*36u + (unsigned)s] = lut[d];           // <=10 distinct addrs: multicast
            }
        }
    }
    __syncthreads();

    // ---- phase 2: attention + epilogue for t = tyu + 7j, j=0..4 (t=34 pad ok)
    {
        const int tyu = __builtin_amdgcn_readfirstlane(ty);  // wave-uniform
        const uint4* __restrict__ srow4 = (const uint4*)(su + lane*36);
        const float* __restrict__ Pb = ws + PW_OFF + tyu*36; // + j*252 + s (s_load imm)

        float mx[5] = {0,0,0,0,0}, my[5] = {0,0,0,0,0};
        #pragma unroll
        for (int s4 = 0; s4 < 9; ++s4) {
            uint4 pk4 = srow4[s4];                           // ds_read_b128
            #pragma unroll
            for (int k = 0; k < 4; ++k) {
                unsigned pk = (k==0) ? pk4.x : (k==1) ? pk4.y : (k==2) ? pk4.z : pk4.w;
                float ux = __uint_as_float(pk << 16);
                float uy = __uint_as_float(pk & 0xffff0000u);
                int s = s4*4 + k;
                #pragma unroll
                for (int j = 0; j < 5; ++j) {
                    float P = Pb[j*252 + s];                 // rows/cols >=34 are zero
                    mx[j] = fmaf(P, ux, mx[j]);
                    my[j] = fmaf(P, uy, my[j]);
                }
            }
        }

        const float hA0 = ws[HA_OFF], hA1 = ws[HA_OFF+1];
        const float w0=wn[0], w1=wn[1], w2=wn[2], w3=wn[3], w4=wn[4];
        const float ob0=opB[0], ob1=opB[1], ob2=opB[2], ob3=opB[3], ob4=opB[4];
        const unsigned* __restrict__ srow = su + lane*36;

        #pragma unroll
        for (int j = 0; j < 5; ++j) {
            const int t = tyu + 7*j;           // uniform; t=34 -> pad slots
            float g = mx[j]*hA0 + my[j]*hA1;   // out5 @ out_proj_A (collapsed)
            unsigned pkt = srow[t];
            float x0 = __uint_as_float(pkt << 16)         + g*ob0;
            float x1 = __uint_as_float(pkt & 0xffff0000u) + g*ob1;
            float x2 = ws[POS_OFF + 4*t + 0] + g*ob2;
            float x3 = ws[POS_OFF + 4*t + 1] + g*ob3;
            float x4 = ws[POS_OFF + 4*t + 2] + g*ob4;

            float inv1 = rsqrtf((x0*x0+x1*x1+x2*x2+x3*x3+x4*x4)*0.2f + 1e-5f);
            float h0=x0*inv1*w0, h1=x1*inv1*w1, h2=x2*inv1*w2, h3=x3*inv1*w3, h4=x4*inv1*w4;
            float z0 = h0*fc1[0]+h1*fc1[1]+h2*fc1[2]+h3*fc1[3]+h4*fc1[4];
            float z1 = h0*fc1[5]+h1*fc1[6]+h2*fc1[7]+h3*fc1[8]+h4*fc1[9];
            float g0 = gelu_fast(z0);
            float g1 = gelu_fast(z1);
            x0 += g0*H[0] + g1*H[5];
            x1 += g0*H[1] + g1*H[6];
            x2 += g0*H[2] + g1*H[7];
            x3 += g0*H[3] + g1*H[8];
            x4 += g0*H[4] + g1*H[9];
            float inv2 = rsqrtf((x0*x0+x1*x1+x2*x2+x3*x3+x4*x4)*0.2f + 1e-5f);
            h0=x0*inv2*w0; h1=x1*inv2*w1; h2=x2*inv2*w2; h3=x3*inv2*w3; h4=x4*inv2*w4;
            float p0 = h0*H[0]+h1*H[1]+h2*H[2]+h3*H[3]+h4*H[4];
            float p1 = h0*H[5]+h1*H[6]+h2*H[7]+h3*H[8]+h4*H[9];
            prv[lane*35 + t] = make_float2(p0, p1);   // t=34 -> pad, never read
        }
    }
    __syncthreads();

    // ---- phase 3: lane-consecutive nontemporal float4 write of the span
    {
        vfloat4* __restrict__ o4 = (vfloat4*)out + (size_t)b0*85;  // 340 f/row
        for (int e4 = tid; e4 < 5440; e4 += 448) {                 // 64*85
            int bp = e4 / 85;
            int r4 = e4 - 85*bp;
            int f0 = 4*r4;
            int ta = f0 / 10;
            int tb = (f0 + 3) / 10;          // ta or ta+1
            float2 pa = prv[bp*35 + ta];
            float2 pb = prv[bp*35 + tb];
            vfloat4 v;
            #pragma unroll
            for (int k = 0; k < 4; ++k) {
                int f = f0 + k;
                int t = f / 10;
                int c = f - 10*t;
                float2 p = (t == ta) ? pa : pb;
                v[k] = p.x*stk[2*c] + p.y*stk[2*c+1];
            }
            __builtin_nontemporal_store(v, &o4[e4]);
        }
    }
}

extern "C" void kernel_launch(void* const* d_in, const int* in_sizes, int n_in,
                              void* d_out, int out_size, void* d_ws, size_t ws_size,
                              hipStream_t stream)
{
    const int*   idx  = (const int*)  d_in[0];
    const float* pA   = (const float*)d_in[1];   // tok_arc_A
    const float* pSt  = (const float*)d_in[2];   // tok_arc_start
    const float* pSd  = (const float*)d_in[3];   // tok_arc_stride
    const float* zhi  = (const float*)d_in[4];   // z_hi_pos (3)
    const float* spe  = (const float*)d_in[5];   // special_pos_equals (3)
    const float* qw   = (const float*)d_in[6];   // q_proj_w (4x3)
    const float* qph  = (const float*)d_in[7];   // q_phase_angle (1)
    const float* opA  = (const float*)d_in[8];   // out_proj_A (5x1)
    const float* opB  = (const float*)d_in[9];   // out_proj_B (1x5)
    const float* wn   = (const float*)d_in[10];  // norm_weight (5)
    const float* fc1  = (const float*)d_in[11];  // fc1_w (2x5)
    const float* H    = (const float*)d_in[12];  // head_proj_w (2x5)
    float* ws  = (float*)d_ws;
    float* out = (float*)d_out;

    hipLaunchKernelGGL(prep_kernel, dim3(34), dim3(64), 0, stream,
                       pA, pSt, pSd, zhi, spe, qw, qph, opA, wn, H, ws);
    hipLaunchKernelGGL(micro_kernel, dim3(1024), dim3(64, 7), 0, stream,
                       idx, pA, pSt, pSd, opB, wn, fc1, H, ws, out);
}